// Round 5
// baseline (708.118 us; speedup 1.0000x reference)
//
#include <hip/hip_runtime.h>
#include <stdint.h>
#include <stddef.h>

typedef __bf16 bf16;
typedef __bf16 bf16x8 __attribute__((ext_vector_type(8)));
typedef __bf16 bf16x4 __attribute__((ext_vector_type(4)));
typedef float  f32x4  __attribute__((ext_vector_type(4)));

#define NB      4096        // batch
#define NF      4096        // features (= K = N for all GEMMs)
#define NCODES  (NB * NF / 64)   // 262144
#define NEMB    512
#define EDIM    64

// ---------------------------------------------------------------- helpers
__device__ __forceinline__ void gld_lds16(const void* g, void* l) {
  __builtin_amdgcn_global_load_lds(
      (const __attribute__((address_space(1))) void*)g,
      (__attribute__((address_space(3))) void*)l, 16, 0, 0);
}

// ---------------------------------------------------------------- f32 -> bf16 convert
__global__ void cvt_f32_bf16(const float* __restrict__ in, bf16* __restrict__ out, int n8) {
  int idx = blockIdx.x * blockDim.x + threadIdx.x;
  int stride = gridDim.x * blockDim.x;
  for (int i = idx; i < n8; i += stride) {
    const float4* p = (const float4*)(in + (size_t)i * 8);
    float4 a = p[0], b = p[1];
    bf16x8 o;
    o[0] = (bf16)a.x; o[1] = (bf16)a.y; o[2] = (bf16)a.z; o[3] = (bf16)a.w;
    o[4] = (bf16)b.x; o[5] = (bf16)b.y; o[6] = (bf16)b.z; o[7] = (bf16)b.w;
    *(bf16x8*)(out + (size_t)i * 8) = o;
  }
}

// ---------------------------------------------------------------- codebook prep: bf16 copy + row norms
__global__ void cbprep(const float* __restrict__ cb, bf16* __restrict__ cbbf,
                       float* __restrict__ cbnorm) {
  int r = blockIdx.x * blockDim.x + threadIdx.x;
  if (r < NEMB) {
    float s = 0.f;
    for (int d = 0; d < EDIM; ++d) {
      float v = cb[r * EDIM + d];
      s += v * v;
      cbbf[r * EDIM + d] = (bf16)v;
    }
    cbnorm[r] = s;
  }
}

// ---------------------------------------------------------------- GEMM 256x256, 8-phase/2-tile
// pipeline, balanced 4/8/8/4 ds_reads, hoisted per-lane LDS bases (all reads are
// base + compile-time imm), uniform vmcnt(4) at P1/P3/P5/P7, stages:
// P1:B0(t+2) P2:B1(t+2) P3:A0+A1(t+2) (P0/P4 stage-free).
#define BAR()   __builtin_amdgcn_s_barrier()
#define LGKM(n) asm volatile("s_waitcnt lgkmcnt(" #n ")" ::: "memory")
#define VMC(n)  asm volatile("s_waitcnt vmcnt(" #n ")" ::: "memory")
#define PRIO(n) __builtin_amdgcn_s_setprio(n)

// A-quad q: frag rows 2q*16, (2q+1)*16. 4 ds_read_b128.
#define RD_A(d0, d1, base, q) do {                                        \
    d0[0] = *(const bf16x8*)((base) + (2*(q))*1024   + boff0);            \
    d1[0] = *(const bf16x8*)((base) + (2*(q))*1024   + boff1);            \
    d0[1] = *(const bf16x8*)((base) + (2*(q)+1)*1024 + boff0);            \
    d1[1] = *(const bf16x8*)((base) + (2*(q)+1)*1024 + boff1); } while (0)

// B frags j0, j0+1. 4 ds_read_b128.
#define RD_B2(d0, d1, base, j0) do {                                      \
    d0[j0]   = *(const bf16x8*)((base) + (j0)*1024     + boff0);          \
    d1[j0]   = *(const bf16x8*)((base) + (j0)*1024     + boff1);          \
    d0[j0+1] = *(const bf16x8*)((base) + ((j0)+1)*1024 + boff0);          \
    d1[j0+1] = *(const bf16x8*)((base) + ((j0)+1)*1024 + boff1); } while (0)

#define MFMA_Q(q, x0, x1, y0, y1) do {                               \
    _Pragma("unroll")                                                \
    for (int i2 = 0; i2 < 2; ++i2) {                                 \
      _Pragma("unroll")                                              \
      for (int j = 0; j < 4; ++j) {                                  \
        acc[2*(q)+i2][j] = __builtin_amdgcn_mfma_f32_16x16x32_bf16(  \
            x0[i2], y0[j], acc[2*(q)+i2][j], 0, 0, 0);               \
        acc[2*(q)+i2][j] = __builtin_amdgcn_mfma_f32_16x16x32_bf16(  \
            x1[i2], y1[j], acc[2*(q)+i2][j], 0, 0, 0);               \
      } } } while (0)

template<int OUTMODE, int RELU>   // OUTMODE: 0 f32, 1 bf16
__global__ __launch_bounds__(512, 2)
void gemm256(const bf16* __restrict__ A, const bf16* __restrict__ W,
             const float* __restrict__ bias,
             float* __restrict__ outF, bf16* __restrict__ outB) {
  constexpr int K = 4096, N = 4096, NT = 64;
  __shared__ bf16 AS[2][2][128 * 64];
  __shared__ bf16 BS[2][2][128 * 64];

  const int tid = threadIdx.x;
  const int wave = tid >> 6, lane = tid & 63;
  const int l15 = lane & 15, lg = lane >> 4;
  const int wm = wave >> 2, wn = wave & 3;
  const int rb0 = (wn & 1) * 64;

  // XCD-bijective swizzle (256 blocks, 256 % 8 == 0)
  const int bid = blockIdx.x;
  const int lb  = (bid & 7) * 32 + (bid >> 3);
  const int bx = lb & 15, by = lb >> 4;
  const int brow = by * 256, bcol = bx * 256;

  // hoisted per-lane ds_read bases: frag rows are 16-multiples -> swizzle slot
  // depends only on l15: slot0 = lg^(l15&7); chunk-high slot = slot0^4 -> boff^32.
  const int boff0 = l15 * 64 + ((lg ^ (l15 & 7)) * 8);
  const int boff1 = boff0 ^ 32;

  // staging: thread covers units u1,u2 of each 1024-unit half-tile
  const int u1 = tid,       r1 = u1 >> 3, ss1 = (u1 & 7) ^ (r1 & 7);
  const int u2 = tid + 512, r2 = u2 >> 3, ss2 = (u2 & 7) ^ (r2 & 7);
  const size_t tofs1 = (size_t)r1 * K + ss1 * 8;
  const size_t tofs2 = (size_t)r2 * K + ss2 * 8;
  const bf16* gW0 = W + (size_t)bcol * K;
  const bf16* gW1 = W + (size_t)(bcol + 128) * K;
  const bf16* gA0 = A + (size_t)brow * K;
  const bf16* gA1 = A + (size_t)(brow + 128) * K;

#define STAGE(gptr, k_, ldsh) do {                                        \
    gld_lds16((gptr) + tofs1 + (size_t)(k_) * 64, (ldsh) + u1 * 8);       \
    gld_lds16((gptr) + tofs2 + (size_t)(k_) * 64, (ldsh) + u2 * 8); } while (0)

  bf16* as00 = &AS[0][0][0]; bf16* as01 = &AS[0][1][0];
  bf16* as10 = &AS[1][0][0]; bf16* as11 = &AS[1][1][0];
  bf16* bs00 = &BS[0][0][0]; bf16* bs01 = &BS[0][1][0];
  bf16* bs10 = &BS[1][0][0]; bf16* bs11 = &BS[1][1][0];

  // wave-local read bases (B cols: fold rb0 row offset in)
  const bf16* Ae = &AS[0][wm][0];
  const bf16* Ao = &AS[1][wm][0];
  const bf16* Be = &BS[0][wn >> 1][rb0 * 64];
  const bf16* Bo = &BS[1][wn >> 1][rb0 * 64];

  f32x4 acc[8][4];
#pragma unroll
  for (int i = 0; i < 8; ++i)
#pragma unroll
    for (int j = 0; j < 4; ++j)
      acc[i][j] = f32x4{0.f, 0.f, 0.f, 0.f};

  bf16x8 bE0[4], bE1[4], bO0[4], bO1[4];
  bf16x8 aP0[2], aP1[2], aQ0[2], aQ1[2];

  // prologue: stage tiles 0,1 fully (16 glds); tile0 certified by vmcnt(8)
  STAGE(gW0, 0, bs00); STAGE(gW1, 0, bs01);
  STAGE(gA0, 0, as00); STAGE(gA1, 0, as01);
  STAGE(gW0, 1, bs10); STAGE(gW1, 1, bs11);
  STAGE(gA0, 1, as10); STAGE(gA1, 1, as11);
  VMC(8);
  BAR();
  RD_B2(bE0, bE1, Be, 0);
  RD_B2(bE0, bE1, Be, 2);
  RD_A(aP0, aP1, Ae, 0);

  for (int kt = 0; kt < NT; kt += 2) {
    const int k2 = (kt + 2 < NT) ? (kt + 2) : kt;       // same-parity identical rewrite at tail
    const int k3 = (kt + 3 < NT) ? (kt + 3) : (kt + 1);

    // P0: read A(T0,q1); MFMA T0q0
    RD_A(aQ0, aQ1, Ae, 1);
    BAR(); LGKM(4); PRIO(1); MFMA_Q(0, aP0, aP1, bE0, bE1); PRIO(0); BAR();

    // P1: cert {B(T1)}; stage B0(T2); read B(T1)j01 + A(T0,q2); MFMA T0q1
    VMC(4);
    STAGE(gW0, k2, bs00);
    RD_B2(bO0, bO1, Bo, 0);
    RD_A(aP0, aP1, Ae, 2);
    BAR(); LGKM(8); PRIO(1); MFMA_Q(1, aQ0, aQ1, bE0, bE1); PRIO(0); BAR();

    // P2: stage B1(T2); read B(T1)j23 + A(T0,q3); MFMA T0q2
    STAGE(gW1, k2, bs01);
    RD_B2(bO0, bO1, Bo, 2);
    RD_A(aQ0, aQ1, Ae, 3);
    BAR(); LGKM(8); PRIO(1); MFMA_Q(2, aP0, aP1, bE0, bE1); PRIO(0); BAR();

    // P3: cert {A(T1)}; stage A0+A1(T2); read A(T1,q0); MFMA T0q3
    VMC(4);
    STAGE(gA0, k2, as00); STAGE(gA1, k2, as01);
    RD_A(aP0, aP1, Ao, 0);
    BAR(); LGKM(4); PRIO(1); MFMA_Q(3, aQ0, aQ1, bE0, bE1); PRIO(0); BAR();

    // P4: read A(T1,q1); MFMA T1q0
    RD_A(aQ0, aQ1, Ao, 1);
    BAR(); LGKM(4); PRIO(1); MFMA_Q(0, aP0, aP1, bO0, bO1); PRIO(0); BAR();

    // P5: cert {B(T2)}; stage B0(T3); read B(T2)j01 + A(T1,q2); MFMA T1q1
    VMC(4);
    STAGE(gW0, k3, bs10);
    RD_B2(bE0, bE1, Be, 0);
    RD_A(aP0, aP1, Ao, 2);
    BAR(); LGKM(8); PRIO(1); MFMA_Q(1, aQ0, aQ1, bO0, bO1); PRIO(0); BAR();

    // P6: stage B1(T3); read B(T2)j23 + A(T1,q3); MFMA T1q2
    STAGE(gW1, k3, bs11);
    RD_B2(bE0, bE1, Be, 2);
    RD_A(aQ0, aQ1, Ao, 3);
    BAR(); LGKM(8); PRIO(1); MFMA_Q(2, aP0, aP1, bO0, bO1); PRIO(0); BAR();

    // P7: cert {A(T2)}; stage A0+A1(T3); read A(T2,q0); MFMA T1q3
    VMC(4);
    STAGE(gA0, k3, as10); STAGE(gA1, k3, as11);
    RD_A(aP0, aP1, Ae, 0);
    BAR(); LGKM(4); PRIO(1); MFMA_Q(3, aQ0, aQ1, bO0, bO1); PRIO(0); BAR();
  }
#undef STAGE

  // epilogue: C/D layout col = lane&15, row = (lane>>4)*4 + reg
#pragma unroll
  for (int j = 0; j < 4; ++j) {
    int col = bcol + wn * 64 + j * 16 + l15;
    float bv = bias[col];
#pragma unroll
    for (int i = 0; i < 8; ++i) {
#pragma unroll
      for (int rr = 0; rr < 4; ++rr) {
        int row = brow + wm * 128 + i * 16 + lg * 4 + rr;
        float v = acc[i][j][rr] + bv;
        if (RELU) v = fmaxf(v, 0.f);
        size_t o = (size_t)row * N + col;
        if (OUTMODE == 0) outF[o] = v;
        else              outB[o] = (bf16)v;
      }
    }
  }
}

// ---------------------------------------------------------------- VQ: LDS codebook, 4-group ILP,
// packed-key argmin reduce, 1 SSE atomic/block, per-block hist flush.
__global__ __launch_bounds__(512, 2)
void vq_kernel(const float* __restrict__ latent,
               const float* __restrict__ cb, const bf16* __restrict__ cbbf_g,
               const float* __restrict__ cbnorm_g,
               bf16* __restrict__ qbf, unsigned int* __restrict__ hist,
               float* __restrict__ sse_out) {
  __shared__ bf16     cbl[NEMB * EDIM];   // 64 KB, XOR-swizzled at 16B granularity
  __shared__ float    cnl[NEMB];
  __shared__ unsigned lhist[NEMB];
  __shared__ float    swse[8];

  const int tid = threadIdx.x;
  lhist[tid] = 0;
  cnl[tid] = cbnorm_g[tid];
  {
    const uint4* src = (const uint4*)cbbf_g;   // 4096 16B units
    uint4* dst = (uint4*)cbl;
#pragma unroll
    for (int i = 0; i < 8; ++i) {
      int u = tid + i * 512;
      dst[u ^ ((u >> 3) & 7)] = src[u];
    }
  }
  __syncthreads();

  const int wave = tid >> 6, lane = tid & 63;
  const int l15 = lane & 15, lg = lane >> 4;
  const int base = blockIdx.x * 512 + wave * 64;

  bf16x8 a0[4], a1[4];
#pragma unroll
  for (int g = 0; g < 4; ++g) {
    const float* ap = latent + (size_t)(base + g * 16 + l15) * EDIM + lg * 8;
    float4 f0 = *(const float4*)(ap);
    float4 f1 = *(const float4*)(ap + 4);
    float4 f2 = *(const float4*)(ap + 32);
    float4 f3 = *(const float4*)(ap + 36);
    bf16x8 t0, t1;
    t0[0]=(bf16)f0.x; t0[1]=(bf16)f0.y; t0[2]=(bf16)f0.z; t0[3]=(bf16)f0.w;
    t0[4]=(bf16)f1.x; t0[5]=(bf16)f1.y; t0[6]=(bf16)f1.z; t0[7]=(bf16)f1.w;
    t1[0]=(bf16)f2.x; t1[1]=(bf16)f2.y; t1[2]=(bf16)f2.z; t1[3]=(bf16)f2.w;
    t1[4]=(bf16)f3.x; t1[5]=(bf16)f3.y; t1[6]=(bf16)f3.z; t1[7]=(bf16)f3.w;
    a0[g] = t0; a1[g] = t1;
  }

  float best[4][4];
  int   bidx[4][4];
#pragma unroll
  for (int g = 0; g < 4; ++g)
#pragma unroll
    for (int r = 0; r < 4; ++r) { best[g][r] = 1e30f; bidx[g][r] = 0; }

  for (int ct = 0; ct < 32; ++ct) {
    const int row = ct * 16 + l15;
    const int u0 = ((row << 3) + lg) ^ (row & 7);
    bf16x8 b0 = *(const bf16x8*)(cbl + u0 * 8);
    bf16x8 b1 = *(const bf16x8*)(cbl + (u0 ^ 4) * 8);
    float cn = cnl[row];
    int   c  = row;
#pragma unroll
    for (int g = 0; g < 4; ++g) {
      f32x4 acc = f32x4{0.f, 0.f, 0.f, 0.f};
      acc = __builtin_amdgcn_mfma_f32_16x16x32_bf16(a0[g], b0, acc, 0, 0, 0);
      acc = __builtin_amdgcn_mfma_f32_16x16x32_bf16(a1[g], b1, acc, 0, 0, 0);
#pragma unroll
      for (int r = 0; r < 4; ++r) {
        float s = fmaf(-2.0f, acc[r], cn);
        if (s < best[g][r]) { best[g][r] = s; bidx[g][r] = c; }
      }
    }
  }

  float sse = 0.f;
#pragma unroll
  for (int g = 0; g < 4; ++g) {
#pragma unroll
    for (int r = 0; r < 4; ++r) {
      uint32_t bits = __float_as_uint(best[g][r]);
      uint32_t u = bits ^ ((uint32_t)((int32_t)bits >> 31) | 0x80000000u);
      uint32_t key = (u & 0xFFFFFE00u) | (uint32_t)bidx[g][r];
#pragma unroll
      for (int m = 1; m < 16; m <<= 1) {
        uint32_t o = __shfl_xor(key, m);
        key = (o < key) ? o : key;
      }
      int idx = (int)(key & 511u);
      int rowg = base + g * 16 + lg * 4 + r;
      float4 cv = *(const float4*)(latent + (size_t)rowg * EDIM + l15 * 4);
      float4 e  = *(const float4*)(cb + (size_t)idx * EDIM + l15 * 4);
      float d0 = e.x - cv.x, d1 = e.y - cv.y, d2 = e.z - cv.z, d3 = e.w - cv.w;
      sse += d0 * d0 + d1 * d1 + d2 * d2 + d3 * d3;
      bf16x4 q;
      q[0] = (bf16)e.x; q[1] = (bf16)e.y; q[2] = (bf16)e.z; q[3] = (bf16)e.w;
      *(bf16x4*)(qbf + (size_t)rowg * EDIM + l15 * 4) = q;
      if (l15 == 0) atomicAdd(&lhist[idx], 1u);
    }
  }

#pragma unroll
  for (int m = 1; m < 64; m <<= 1) sse += __shfl_xor(sse, m);
  if (lane == 0) swse[wave] = sse;
  __syncthreads();

  unsigned v = lhist[tid];
  if (v) atomicAdd(hist + tid, v);
  if (tid == 0) {
    float s = 0.f;
#pragma unroll
    for (int w = 0; w < 8; ++w) s += swse[w];
    atomicAdd(sse_out, s);
  }
}

// ---------------------------------------------------------------- finalize: vq_loss + perplexity
__global__ void finalize_k(const unsigned* __restrict__ hist, const float* __restrict__ sse,
                           float* __restrict__ out_tail) {
  __shared__ float red[512];
  int t = threadIdx.x;
  float p = (float)hist[t] * (1.0f / (float)NCODES);
  red[t] = p * logf(p + 1e-10f);
  __syncthreads();
  for (int s = 256; s > 0; s >>= 1) {
    if (t < s) red[t] += red[t + s];
    __syncthreads();
  }
  if (t == 0) {
    out_tail[0] = 1.25f * sse[0] * (1.0f / ((float)NCODES * (float)EDIM));
    out_tail[1] = expf(-red[0]);
  }
}

// ---------------------------------------------------------------- launch
extern "C" void kernel_launch(void* const* d_in, const int* in_sizes, int n_in,
                              void* d_out, int out_size, void* d_ws, size_t ws_size,
                              hipStream_t stream) {
  const float* x  = (const float*)d_in[0];
  const float* W1 = (const float*)d_in[1];
  const float* b1 = (const float*)d_in[2];
  const float* W2 = (const float*)d_in[3];
  const float* b2 = (const float*)d_in[4];
  const float* W3 = (const float*)d_in[5];
  const float* b3 = (const float*)d_in[6];
  const float* W4 = (const float*)d_in[7];
  const float* b4 = (const float*)d_in[8];
  const float* cb = (const float*)d_in[9];
  float* out = (float*)d_out;

  char* ws = (char*)d_ws;
  float*    sse    = (float*)(ws + 0);
  unsigned* hist   = (unsigned*)(ws + 1024);
  float*    cbnorm = (float*)(ws + 4096);
  bf16*     cbbf   = (bf16*)(ws + 8192);
  size_t off = 131072;
  bf16* xbf  = (bf16*)(ws + off);  off += (size_t)NB * NF * 2;
  bf16* wbuf = (bf16*)(ws + off);  off += (size_t)NB * NF * 2;
  bf16* hbf  = (bf16*)(ws + off);  off += (size_t)NB * NF * 2;
  float* latent = (float*)(ws + off); off += (size_t)NB * NF * 4;
  bf16* qbf  = xbf;   // alias: x dead after GEMM1
  bf16* h2bf = hbf;   // alias: h dead after GEMM2

  hipMemsetAsync(ws, 0, 3072, stream);  // sse + hist

  const int n8 = NB * NF / 8;
  cvt_f32_bf16<<<dim3(2048), dim3(256), 0, stream>>>(x,  xbf,  n8);
  cvt_f32_bf16<<<dim3(2048), dim3(256), 0, stream>>>(W1, wbuf, n8);
  cbprep<<<dim3(2), dim3(256), 0, stream>>>(cb, cbbf, cbnorm);

  dim3 ggrid(256), gblock(512);
  // h = relu(x @ W1^T + b1) -> bf16
  gemm256<1, 1><<<ggrid, gblock, 0, stream>>>(xbf, wbuf, b1, (float*)nullptr, hbf);
  cvt_f32_bf16<<<dim3(2048), dim3(256), 0, stream>>>(W2, wbuf, n8);
  // latent = h @ W2^T + b2 -> f32
  gemm256<0, 0><<<ggrid, gblock, 0, stream>>>(hbf, wbuf, b2, latent, (bf16*)nullptr);
  // VQ
  vq_kernel<<<dim3(512), dim3(512), 0, stream>>>(latent, cb, cbbf, cbnorm, qbf, hist, sse);
  cvt_f32_bf16<<<dim3(2048), dim3(256), 0, stream>>>(W3, wbuf, n8);
  // h2 = relu(q @ W3^T + b3) -> bf16
  gemm256<1, 1><<<ggrid, gblock, 0, stream>>>(qbf, wbuf, b3, (float*)nullptr, h2bf);
  cvt_f32_bf16<<<dim3(2048), dim3(256), 0, stream>>>(W4, wbuf, n8);
  // recons = h2 @ W4^T + b4 -> f32 (d_out)
  gemm256<0, 0><<<ggrid, gblock, 0, stream>>>(h2bf, wbuf, b4, out, (bf16*)nullptr);

  finalize_k<<<dim3(1), dim3(512), 0, stream>>>(hist, sse, out + (size_t)NB * NF);
}

// Round 6
// 603.952 us; speedup vs baseline: 1.1725x; 1.1725x over previous
//
#include <hip/hip_runtime.h>
#include <stdint.h>
#include <stddef.h>

typedef __bf16 bf16;
typedef __bf16 bf16x8 __attribute__((ext_vector_type(8)));
typedef __bf16 bf16x4 __attribute__((ext_vector_type(4)));
typedef float  f32x4  __attribute__((ext_vector_type(4)));

#define NB      4096        // batch
#define NF      4096        // features (= K = N for all GEMMs)
#define NCODES  (NB * NF / 64)   // 262144
#define NEMB    512
#define EDIM    64

// ---------------------------------------------------------------- helpers
__device__ __forceinline__ void gld_lds16(const void* g, void* l) {
  __builtin_amdgcn_global_load_lds(
      (const __attribute__((address_space(1))) void*)g,
      (__attribute__((address_space(3))) void*)l, 16, 0, 0);
}

// ---------------------------------------------------------------- f32 -> bf16 convert
__global__ void cvt_f32_bf16(const float* __restrict__ in, bf16* __restrict__ out, int n8) {
  int idx = blockIdx.x * blockDim.x + threadIdx.x;
  int stride = gridDim.x * blockDim.x;
  for (int i = idx; i < n8; i += stride) {
    const float4* p = (const float4*)(in + (size_t)i * 8);
    float4 a = p[0], b = p[1];
    bf16x8 o;
    o[0] = (bf16)a.x; o[1] = (bf16)a.y; o[2] = (bf16)a.z; o[3] = (bf16)a.w;
    o[4] = (bf16)b.x; o[5] = (bf16)b.y; o[6] = (bf16)b.z; o[7] = (bf16)b.w;
    *(bf16x8*)(out + (size_t)i * 8) = o;
  }
}

// ---------------------------------------------------------------- codebook prep: bf16 copy + row norms
__global__ void cbprep(const float* __restrict__ cb, bf16* __restrict__ cbbf,
                       float* __restrict__ cbnorm) {
  int r = blockIdx.x * blockDim.x + threadIdx.x;
  if (r < NEMB) {
    float s = 0.f;
    for (int d = 0; d < EDIM; ++d) {
      float v = cb[r * EDIM + d];
      s += v * v;
      cbbf[r * EDIM + d] = (bf16)v;
    }
    cbnorm[r] = s;
  }
}

// ---------------------------------------------------------------- GEMM 256x256, 8-phase/2-tile
// R4 schedule (vmcnt(4) at P3/P7, stages 2-glds/phase, LGKM(12) burst phases)
// + hoisted per-lane addressing (boff0/boff1 compile-time-imm ds_reads; precomputed
// staging offsets). 8 waves (2Mx4N), per-wave 128x64 out, BK=64, 16B-slot XOR swizzle.
#define BAR()   __builtin_amdgcn_s_barrier()
#define LGKM(n) asm volatile("s_waitcnt lgkmcnt(" #n ")" ::: "memory")
#define VMC(n)  asm volatile("s_waitcnt vmcnt(" #n ")" ::: "memory")
#define PRIO(n) __builtin_amdgcn_s_setprio(n)

// A-quad q: frag rows 2q*16, (2q+1)*16. 4 ds_read_b128, base + compile-time imm.
#define RD_A(d0, d1, base, q) do {                                        \
    d0[0] = *(const bf16x8*)((base) + (2*(q))*1024   + boff0);            \
    d1[0] = *(const bf16x8*)((base) + (2*(q))*1024   + boff1);            \
    d0[1] = *(const bf16x8*)((base) + (2*(q)+1)*1024 + boff0);            \
    d1[1] = *(const bf16x8*)((base) + (2*(q)+1)*1024 + boff1); } while (0)

// B frags j0, j0+1. 4 ds_read_b128.
#define RD_B2(d0, d1, base, j0) do {                                      \
    d0[j0]   = *(const bf16x8*)((base) + (j0)*1024     + boff0);          \
    d1[j0]   = *(const bf16x8*)((base) + (j0)*1024     + boff1);          \
    d0[j0+1] = *(const bf16x8*)((base) + ((j0)+1)*1024 + boff0);          \
    d1[j0+1] = *(const bf16x8*)((base) + ((j0)+1)*1024 + boff1); } while (0)

#define MFMA_Q(q, x0, x1, y0, y1) do {                               \
    _Pragma("unroll")                                                \
    for (int i2 = 0; i2 < 2; ++i2) {                                 \
      _Pragma("unroll")                                              \
      for (int j = 0; j < 4; ++j) {                                  \
        acc[2*(q)+i2][j] = __builtin_amdgcn_mfma_f32_16x16x32_bf16(  \
            x0[i2], y0[j], acc[2*(q)+i2][j], 0, 0, 0);               \
        acc[2*(q)+i2][j] = __builtin_amdgcn_mfma_f32_16x16x32_bf16(  \
            x1[i2], y1[j], acc[2*(q)+i2][j], 0, 0, 0);               \
      } } } while (0)

template<int OUTMODE, int RELU>   // OUTMODE: 0 f32, 1 bf16
__global__ __launch_bounds__(512, 2)
void gemm256(const bf16* __restrict__ A, const bf16* __restrict__ W,
             const float* __restrict__ bias,
             float* __restrict__ outF, bf16* __restrict__ outB) {
  constexpr int K = 4096, N = 4096, NT = 64;
  __shared__ bf16 AS[2][2][128 * 64];
  __shared__ bf16 BS[2][2][128 * 64];

  const int tid = threadIdx.x;
  const int wave = tid >> 6, lane = tid & 63;
  const int l15 = lane & 15, lg = lane >> 4;
  const int wm = wave >> 2, wn = wave & 3;
  const int rb0 = (wn & 1) * 64;

  // XCD-bijective swizzle (256 blocks, 256 % 8 == 0)
  const int bid = blockIdx.x;
  const int lb  = (bid & 7) * 32 + (bid >> 3);
  const int bx = lb & 15, by = lb >> 4;
  const int brow = by * 256, bcol = bx * 256;

  // hoisted per-lane ds_read bases: frag rows are 16-multiples -> swizzle slot
  // depends only on l15: slot0 = lg^(l15&7); high chunk slot = slot0^4 -> ^32 bytes.
  const int boff0 = l15 * 64 + ((lg ^ (l15 & 7)) * 8);
  const int boff1 = boff0 ^ 32;

  // staging: thread covers units u1,u2 of each 1024-unit half-tile
  const int u1 = tid,       r1 = u1 >> 3, ss1 = (u1 & 7) ^ (r1 & 7);
  const int u2 = tid + 512, r2 = u2 >> 3, ss2 = (u2 & 7) ^ (r2 & 7);
  const size_t tofs1 = (size_t)r1 * K + ss1 * 8;
  const size_t tofs2 = (size_t)r2 * K + ss2 * 8;
  const bf16* gW0 = W + (size_t)bcol * K;
  const bf16* gW1 = W + (size_t)(bcol + 128) * K;
  const bf16* gA0 = A + (size_t)brow * K;
  const bf16* gA1 = A + (size_t)(brow + 128) * K;

#define STAGE(gptr, k_, ldsh) do {                                        \
    gld_lds16((gptr) + tofs1 + (size_t)(k_) * 64, (ldsh) + u1 * 8);       \
    gld_lds16((gptr) + tofs2 + (size_t)(k_) * 64, (ldsh) + u2 * 8); } while (0)

  bf16* as00 = &AS[0][0][0]; bf16* as01 = &AS[0][1][0];
  bf16* as10 = &AS[1][0][0]; bf16* as11 = &AS[1][1][0];
  bf16* bs00 = &BS[0][0][0]; bf16* bs01 = &BS[0][1][0];
  bf16* bs10 = &BS[1][0][0]; bf16* bs11 = &BS[1][1][0];

  // wave-local read bases (B cols: fold rb0 row offset in)
  const bf16* Ae = &AS[0][wm][0];
  const bf16* Ao = &AS[1][wm][0];
  const bf16* Be = &BS[0][wn >> 1][rb0 * 64];
  const bf16* Bo = &BS[1][wn >> 1][rb0 * 64];

  f32x4 acc[8][4];
#pragma unroll
  for (int i = 0; i < 8; ++i)
#pragma unroll
    for (int j = 0; j < 4; ++j)
      acc[i][j] = f32x4{0.f, 0.f, 0.f, 0.f};

  bf16x8 bE0[4], bE1[4], bO0[4], bO1[4];   // B frag sets (even / odd tile)
  bf16x8 aP0[2], aP1[2], aQ0[2], aQ1[2];   // A frag ping-pong sets

  // prologue: 7 halves (tile0 complete + tile1 B0,B1,A0); vmcnt(6) -> tile0 landed
  STAGE(gW0, 0, bs00); STAGE(gW1, 0, bs01);
  STAGE(gA0, 0, as00); STAGE(gA1, 0, as01);
  STAGE(gW0, 1, bs10); STAGE(gW1, 1, bs11);
  STAGE(gA0, 1, as10);
  VMC(6);
  BAR();
  RD_B2(bE0, bE1, Be, 0);
  RD_B2(bE0, bE1, Be, 2);
  RD_A(aP0, aP1, Ae, 0);

  for (int kt = 0; kt < NT; kt += 2) {
    // ---- P0: read A(T0,q1); stage A1(T1); MFMA T0q0
    RD_A(aQ0, aQ1, Ae, 1);
    STAGE(gA1, kt + 1, as11);
    BAR(); LGKM(4); PRIO(1); MFMA_Q(0, aP0, aP1, bE0, bE1); PRIO(0); BAR();

    // ---- P1: read A(T0,q2); stage B0(T2); MFMA T0q1
    RD_A(aP0, aP1, Ae, 2);
    STAGE(gW0, (kt + 2) & (NT - 1), bs00);
    BAR(); LGKM(4); PRIO(1); MFMA_Q(1, aQ0, aQ1, bE0, bE1); PRIO(0); BAR();

    // ---- P2: read A(T0,q3); stage B1(T2); MFMA T0q2
    RD_A(aQ0, aQ1, Ae, 3);
    STAGE(gW1, (kt + 2) & (NT - 1), bs01);
    BAR(); LGKM(4); PRIO(1); MFMA_Q(2, aP0, aP1, bE0, bE1); PRIO(0); BAR();

    // ---- P3: cert T1; read B(T1)+A(T1,q0); stage A0(T2); MFMA T0q3
    VMC(4);
    RD_B2(bO0, bO1, Bo, 0);
    RD_B2(bO0, bO1, Bo, 2);
    RD_A(aP0, aP1, Ao, 0);
    STAGE(gA0, (kt + 2) & (NT - 1), as00);
    BAR(); LGKM(12); PRIO(1); MFMA_Q(3, aQ0, aQ1, bE0, bE1); PRIO(0); BAR();

    // ---- P4: read A(T1,q1); stage A1(T2); MFMA T1q0
    RD_A(aQ0, aQ1, Ao, 1);
    STAGE(gA1, (kt + 2) & (NT - 1), as01);
    BAR(); LGKM(4); PRIO(1); MFMA_Q(0, aP0, aP1, bO0, bO1); PRIO(0); BAR();

    // ---- P5: read A(T1,q2); stage B0(T3); MFMA T1q1
    RD_A(aP0, aP1, Ao, 2);
    STAGE(gW0, (kt + 3) & (NT - 1), bs10);
    BAR(); LGKM(4); PRIO(1); MFMA_Q(1, aQ0, aQ1, bO0, bO1); PRIO(0); BAR();

    // ---- P6: read A(T1,q3); stage B1(T3); MFMA T1q2
    RD_A(aQ0, aQ1, Ao, 3);
    STAGE(gW1, (kt + 3) & (NT - 1), bs11);
    BAR(); LGKM(4); PRIO(1); MFMA_Q(2, aP0, aP1, bO0, bO1); PRIO(0); BAR();

    // ---- P7: cert T2; read B(T2)+A(T2,q0); stage A0(T3); MFMA T1q3
    VMC(4);
    RD_B2(bE0, bE1, Be, 0);
    RD_B2(bE0, bE1, Be, 2);
    RD_A(aP0, aP1, Ae, 0);
    STAGE(gA0, (kt + 3) & (NT - 1), as10);
    BAR(); LGKM(12); PRIO(1); MFMA_Q(3, aQ0, aQ1, bO0, bO1); PRIO(0); BAR();
  }
#undef STAGE

  // epilogue: C/D layout col = lane&15, row = (lane>>4)*4 + reg
#pragma unroll
  for (int j = 0; j < 4; ++j) {
    int col = bcol + wn * 64 + j * 16 + l15;
    float bv = bias[col];
#pragma unroll
    for (int i = 0; i < 8; ++i) {
#pragma unroll
      for (int rr = 0; rr < 4; ++rr) {
        int row = brow + wm * 128 + i * 16 + lg * 4 + rr;
        float v = acc[i][j][rr] + bv;
        if (RELU) v = fmaxf(v, 0.f);
        size_t o = (size_t)row * N + col;
        if (OUTMODE == 0) outF[o] = v;
        else              outB[o] = (bf16)v;
      }
    }
  }
}

// ---------------------------------------------------------------- VQ: LDS codebook, 4-group ILP,
// packed-key argmin reduce, 1 SSE atomic/block, per-block hist flush.
__global__ __launch_bounds__(512, 2)
void vq_kernel(const float* __restrict__ latent,
               const float* __restrict__ cb, const bf16* __restrict__ cbbf_g,
               const float* __restrict__ cbnorm_g,
               bf16* __restrict__ qbf, unsigned int* __restrict__ hist,
               float* __restrict__ sse_out) {
  __shared__ bf16     cbl[NEMB * EDIM];   // 64 KB, XOR-swizzled at 16B granularity
  __shared__ float    cnl[NEMB];
  __shared__ unsigned lhist[NEMB];
  __shared__ float    swse[8];

  const int tid = threadIdx.x;
  lhist[tid] = 0;
  cnl[tid] = cbnorm_g[tid];
  {
    const uint4* src = (const uint4*)cbbf_g;   // 4096 16B units
    uint4* dst = (uint4*)cbl;
#pragma unroll
    for (int i = 0; i < 8; ++i) {
      int u = tid + i * 512;
      dst[u ^ ((u >> 3) & 7)] = src[u];
    }
  }
  __syncthreads();

  const int wave = tid >> 6, lane = tid & 63;
  const int l15 = lane & 15, lg = lane >> 4;
  const int base = blockIdx.x * 512 + wave * 64;

  bf16x8 a0[4], a1[4];
#pragma unroll
  for (int g = 0; g < 4; ++g) {
    const float* ap = latent + (size_t)(base + g * 16 + l15) * EDIM + lg * 8;
    float4 f0 = *(const float4*)(ap);
    float4 f1 = *(const float4*)(ap + 4);
    float4 f2 = *(const float4*)(ap + 32);
    float4 f3 = *(const float4*)(ap + 36);
    bf16x8 t0, t1;
    t0[0]=(bf16)f0.x; t0[1]=(bf16)f0.y; t0[2]=(bf16)f0.z; t0[3]=(bf16)f0.w;
    t0[4]=(bf16)f1.x; t0[5]=(bf16)f1.y; t0[6]=(bf16)f1.z; t0[7]=(bf16)f1.w;
    t1[0]=(bf16)f2.x; t1[1]=(bf16)f2.y; t1[2]=(bf16)f2.z; t1[3]=(bf16)f2.w;
    t1[4]=(bf16)f3.x; t1[5]=(bf16)f3.y; t1[6]=(bf16)f3.z; t1[7]=(bf16)f3.w;
    a0[g] = t0; a1[g] = t1;
  }

  float best[4][4];
  int   bidx[4][4];
#pragma unroll
  for (int g = 0; g < 4; ++g)
#pragma unroll
    for (int r = 0; r < 4; ++r) { best[g][r] = 1e30f; bidx[g][r] = 0; }

  for (int ct = 0; ct < 32; ++ct) {
    const int row = ct * 16 + l15;
    const int u0 = ((row << 3) + lg) ^ (row & 7);
    bf16x8 b0 = *(const bf16x8*)(cbl + u0 * 8);
    bf16x8 b1 = *(const bf16x8*)(cbl + (u0 ^ 4) * 8);
    float cn = cnl[row];
    int   c  = row;
#pragma unroll
    for (int g = 0; g < 4; ++g) {
      f32x4 acc = f32x4{0.f, 0.f, 0.f, 0.f};
      acc = __builtin_amdgcn_mfma_f32_16x16x32_bf16(a0[g], b0, acc, 0, 0, 0);
      acc = __builtin_amdgcn_mfma_f32_16x16x32_bf16(a1[g], b1, acc, 0, 0, 0);
#pragma unroll
      for (int r = 0; r < 4; ++r) {
        float s = fmaf(-2.0f, acc[r], cn);
        if (s < best[g][r]) { best[g][r] = s; bidx[g][r] = c; }
      }
    }
  }

  float sse = 0.f;
#pragma unroll
  for (int g = 0; g < 4; ++g) {
#pragma unroll
    for (int r = 0; r < 4; ++r) {
      uint32_t bits = __float_as_uint(best[g][r]);
      uint32_t u = bits ^ ((uint32_t)((int32_t)bits >> 31) | 0x80000000u);
      uint32_t key = (u & 0xFFFFFE00u) | (uint32_t)bidx[g][r];
#pragma unroll
      for (int m = 1; m < 16; m <<= 1) {
        uint32_t o = __shfl_xor(key, m);
        key = (o < key) ? o : key;
      }
      int idx = (int)(key & 511u);
      int rowg = base + g * 16 + lg * 4 + r;
      float4 cv = *(const float4*)(latent + (size_t)rowg * EDIM + l15 * 4);
      float4 e  = *(const float4*)(cb + (size_t)idx * EDIM + l15 * 4);
      float d0 = e.x - cv.x, d1 = e.y - cv.y, d2 = e.z - cv.z, d3 = e.w - cv.w;
      sse += d0 * d0 + d1 * d1 + d2 * d2 + d3 * d3;
      bf16x4 q;
      q[0] = (bf16)e.x; q[1] = (bf16)e.y; q[2] = (bf16)e.z; q[3] = (bf16)e.w;
      *(bf16x4*)(qbf + (size_t)rowg * EDIM + l15 * 4) = q;
      if (l15 == 0) atomicAdd(&lhist[idx], 1u);
    }
  }

#pragma unroll
  for (int m = 1; m < 64; m <<= 1) sse += __shfl_xor(sse, m);
  if (lane == 0) swse[wave] = sse;
  __syncthreads();

  unsigned v = lhist[tid];
  if (v) atomicAdd(hist + tid, v);
  if (tid == 0) {
    float s = 0.f;
#pragma unroll
    for (int w = 0; w < 8; ++w) s += swse[w];
    atomicAdd(sse_out, s);
  }
}

// ---------------------------------------------------------------- finalize: vq_loss + perplexity
__global__ void finalize_k(const unsigned* __restrict__ hist, const float* __restrict__ sse,
                           float* __restrict__ out_tail) {
  __shared__ float red[512];
  int t = threadIdx.x;
  float p = (float)hist[t] * (1.0f / (float)NCODES);
  red[t] = p * logf(p + 1e-10f);
  __syncthreads();
  for (int s = 256; s > 0; s >>= 1) {
    if (t < s) red[t] += red[t + s];
    __syncthreads();
  }
  if (t == 0) {
    out_tail[0] = 1.25f * sse[0] * (1.0f / ((float)NCODES * (float)EDIM));
    out_tail[1] = expf(-red[0]);
  }
}

// ---------------------------------------------------------------- launch
extern "C" void kernel_launch(void* const* d_in, const int* in_sizes, int n_in,
                              void* d_out, int out_size, void* d_ws, size_t ws_size,
                              hipStream_t stream) {
  const float* x  = (const float*)d_in[0];
  const float* W1 = (const float*)d_in[1];
  const float* b1 = (const float*)d_in[2];
  const float* W2 = (const float*)d_in[3];
  const float* b2 = (const float*)d_in[4];
  const float* W3 = (const float*)d_in[5];
  const float* b3 = (const float*)d_in[6];
  const float* W4 = (const float*)d_in[7];
  const float* b4 = (const float*)d_in[8];
  const float* cb = (const float*)d_in[9];
  float* out = (float*)d_out;

  char* ws = (char*)d_ws;
  float*    sse    = (float*)(ws + 0);
  unsigned* hist   = (unsigned*)(ws + 1024);
  float*    cbnorm = (float*)(ws + 4096);
  bf16*     cbbf   = (bf16*)(ws + 8192);
  size_t off = 131072;
  bf16* xbf  = (bf16*)(ws + off);  off += (size_t)NB * NF * 2;
  bf16* wbuf = (bf16*)(ws + off);  off += (size_t)NB * NF * 2;
  bf16* hbf  = (bf16*)(ws + off);  off += (size_t)NB * NF * 2;
  float* latent = (float*)(ws + off); off += (size_t)NB * NF * 4;
  bf16* qbf  = xbf;   // alias: x dead after GEMM1
  bf16* h2bf = hbf;   // alias: h dead after GEMM2

  hipMemsetAsync(ws, 0, 3072, stream);  // sse + hist

  const int n8 = NB * NF / 8;
  cvt_f32_bf16<<<dim3(2048), dim3(256), 0, stream>>>(x,  xbf,  n8);
  cvt_f32_bf16<<<dim3(2048), dim3(256), 0, stream>>>(W1, wbuf, n8);
  cbprep<<<dim3(2), dim3(256), 0, stream>>>(cb, cbbf, cbnorm);

  dim3 ggrid(256), gblock(512);
  // h = relu(x @ W1^T + b1) -> bf16
  gemm256<1, 1><<<ggrid, gblock, 0, stream>>>(xbf, wbuf, b1, (float*)nullptr, hbf);
  cvt_f32_bf16<<<dim3(2048), dim3(256), 0, stream>>>(W2, wbuf, n8);
  // latent = h @ W2^T + b2 -> f32
  gemm256<0, 0><<<ggrid, gblock, 0, stream>>>(hbf, wbuf, b2, latent, (bf16*)nullptr);
  // VQ
  vq_kernel<<<dim3(512), dim3(512), 0, stream>>>(latent, cb, cbbf, cbnorm, qbf, hist, sse);
  cvt_f32_bf16<<<dim3(2048), dim3(256), 0, stream>>>(W3, wbuf, n8);
  // h2 = relu(q @ W3^T + b3) -> bf16
  gemm256<1, 1><<<ggrid, gblock, 0, stream>>>(qbf, wbuf, b3, (float*)nullptr, h2bf);
  cvt_f32_bf16<<<dim3(2048), dim3(256), 0, stream>>>(W4, wbuf, n8);
  // recons = h2 @ W4^T + b4 -> f32 (d_out)
  gemm256<0, 0><<<ggrid, gblock, 0, stream>>>(h2bf, wbuf, b4, out, (bf16*)nullptr);

  finalize_k<<<dim3(1), dim3(512), 0, stream>>>(hist, sse, out + (size_t)NB * NF);
}

// Round 7
// 598.598 us; speedup vs baseline: 1.1830x; 1.0089x over previous
//
#include <hip/hip_runtime.h>
#include <stdint.h>
#include <stddef.h>

typedef __bf16 bf16;
typedef __bf16 bf16x8 __attribute__((ext_vector_type(8)));
typedef __bf16 bf16x4 __attribute__((ext_vector_type(4)));
typedef float  f32x4  __attribute__((ext_vector_type(4)));

#define NB      4096        // batch
#define NF      4096        // features (= K = N for all GEMMs)
#define NCODES  (NB * NF / 64)   // 262144
#define NEMB    512
#define EDIM    64

// ---------------------------------------------------------------- helpers
__device__ __forceinline__ void gld_lds16(const void* g, void* l) {
  __builtin_amdgcn_global_load_lds(
      (const __attribute__((address_space(1))) void*)g,
      (__attribute__((address_space(3))) void*)l, 16, 0, 0);
}

// ---------------------------------------------------------------- f32 -> bf16 convert
__global__ void cvt_f32_bf16(const float* __restrict__ in, bf16* __restrict__ out, int n8) {
  int idx = blockIdx.x * blockDim.x + threadIdx.x;
  int stride = gridDim.x * blockDim.x;
  for (int i = idx; i < n8; i += stride) {
    const float4* p = (const float4*)(in + (size_t)i * 8);
    float4 a = p[0], b = p[1];
    bf16x8 o;
    o[0] = (bf16)a.x; o[1] = (bf16)a.y; o[2] = (bf16)a.z; o[3] = (bf16)a.w;
    o[4] = (bf16)b.x; o[5] = (bf16)b.y; o[6] = (bf16)b.z; o[7] = (bf16)b.w;
    *(bf16x8*)(out + (size_t)i * 8) = o;
  }
}

// ---------------------------------------------------------------- codebook prep: bf16 copy + row norms
__global__ void cbprep(const float* __restrict__ cb, bf16* __restrict__ cbbf,
                       float* __restrict__ cbnorm) {
  int r = blockIdx.x * blockDim.x + threadIdx.x;
  if (r < NEMB) {
    float s = 0.f;
    for (int d = 0; d < EDIM; ++d) {
      float v = cb[r * EDIM + d];
      s += v * v;
      cbbf[r * EDIM + d] = (bf16)v;
    }
    cbnorm[r] = s;
  }
}

// ---------------------------------------------------------------- GEMM 256x256, m201-style 8-phase/
// 2-tile: per-phase = one C-quadrant (64x32 of the wave's 128x64), reads in the SAME
// phase as their MFMA (12/8/4/0 pattern, lgkm(8) pre-barrier on the 12-read phase,
// lgkm(0) post-barrier), vmcnt(6) only at phases 4/8. One half-tile staged per phase
// (WAR-ledger-verified rotation). 16B-slot XOR swizzle, hoisted per-lane addressing.
#define BAR()   __builtin_amdgcn_s_barrier()
#define LGKM(n) asm volatile("s_waitcnt lgkmcnt(" #n ")" ::: "memory")
#define VMC(n)  asm volatile("s_waitcnt vmcnt(" #n ")" ::: "memory")
#define PRIO(n) __builtin_amdgcn_s_setprio(n)

// A half rb (64 rows = 4 frags x 2 kk): 8 ds_read_b128 into d0[fr] (kk0), d1[fr] (kk1)
#define RD_A4(d0, d1, base, rb) do {                                          \
    d0[0] = *(const bf16x8*)((base) + (rb)*4096 + 0*1024 + boff0);            \
    d1[0] = *(const bf16x8*)((base) + (rb)*4096 + 0*1024 + boff1);            \
    d0[1] = *(const bf16x8*)((base) + (rb)*4096 + 1*1024 + boff0);            \
    d1[1] = *(const bf16x8*)((base) + (rb)*4096 + 1*1024 + boff1);            \
    d0[2] = *(const bf16x8*)((base) + (rb)*4096 + 2*1024 + boff0);            \
    d1[2] = *(const bf16x8*)((base) + (rb)*4096 + 2*1024 + boff1);            \
    d0[3] = *(const bf16x8*)((base) + (rb)*4096 + 3*1024 + boff0);            \
    d1[3] = *(const bf16x8*)((base) + (rb)*4096 + 3*1024 + boff1); } while (0)

// B col-frags j0, j0+1: 4 ds_read_b128
#define RD_B2(d0, d1, base, j0) do {                                          \
    d0[j0]   = *(const bf16x8*)((base) + (j0)*1024     + boff0);              \
    d1[j0]   = *(const bf16x8*)((base) + (j0)*1024     + boff1);              \
    d0[j0+1] = *(const bf16x8*)((base) + ((j0)+1)*1024 + boff0);              \
    d1[j0+1] = *(const bf16x8*)((base) + ((j0)+1)*1024 + boff1); } while (0)

// C-quadrant MFMA: rows ib..ib+3 (frag), cols jb..jb+1 (frag), 2 kk each = 16 MFMA
#define MQ(ib, jb, A0a, A1a) do {                                             \
    _Pragma("unroll")                                                         \
    for (int fr = 0; fr < 4; ++fr) {                                          \
      _Pragma("unroll")                                                       \
      for (int jc = 0; jc < 2; ++jc) {                                        \
        acc[(ib)+fr][(jb)+jc] = __builtin_amdgcn_mfma_f32_16x16x32_bf16(      \
            A0a[fr], b0[(jb)+jc], acc[(ib)+fr][(jb)+jc], 0, 0, 0);            \
        acc[(ib)+fr][(jb)+jc] = __builtin_amdgcn_mfma_f32_16x16x32_bf16(      \
            A1a[fr], b1[(jb)+jc], acc[(ib)+fr][(jb)+jc], 0, 0, 0);            \
      } } } while (0)

template<int OUTMODE, int RELU>   // OUTMODE: 0 f32, 1 bf16
__global__ __launch_bounds__(512, 2)
void gemm256(const bf16* __restrict__ A, const bf16* __restrict__ W,
             const float* __restrict__ bias,
             float* __restrict__ outF, bf16* __restrict__ outB) {
  constexpr int K = 4096, N = 4096, NT = 64;
  __shared__ bf16 AS[2][2][128 * 64];
  __shared__ bf16 BS[2][2][128 * 64];

  const int tid = threadIdx.x;
  const int wave = tid >> 6, lane = tid & 63;
  const int l15 = lane & 15, lg = lane >> 4;
  const int wm = wave >> 2, wn = wave & 3;
  const int rb0 = (wn & 1) * 64;

  // XCD-bijective swizzle (256 blocks, 256 % 8 == 0)
  const int bid = blockIdx.x;
  const int lb  = (bid & 7) * 32 + (bid >> 3);
  const int bx = lb & 15, by = lb >> 4;
  const int brow = by * 256, bcol = bx * 256;

  // hoisted per-lane ds_read bases (frag rows are 16-multiples -> swizzle slot
  // depends only on l15): kk0 at boff0, kk1 at boff0^32.
  const int boff0 = l15 * 64 + ((lg ^ (l15 & 7)) * 8);
  const int boff1 = boff0 ^ 32;

  // staging: thread covers units u1,u2 of each 1024-unit half-tile
  const int u1 = tid,       r1 = u1 >> 3, ss1 = (u1 & 7) ^ (r1 & 7);
  const int u2 = tid + 512, r2 = u2 >> 3, ss2 = (u2 & 7) ^ (r2 & 7);
  const size_t tofs1 = (size_t)r1 * K + ss1 * 8;
  const size_t tofs2 = (size_t)r2 * K + ss2 * 8;
  const bf16* gW0 = W + (size_t)bcol * K;
  const bf16* gW1 = W + (size_t)(bcol + 128) * K;
  const bf16* gA0 = A + (size_t)brow * K;
  const bf16* gA1 = A + (size_t)(brow + 128) * K;

#define STAGE(gptr, k_, ldsh) do {                                        \
    gld_lds16((gptr) + tofs1 + (size_t)(k_) * 64, (ldsh) + u1 * 8);       \
    gld_lds16((gptr) + tofs2 + (size_t)(k_) * 64, (ldsh) + u2 * 8); } while (0)

  bf16* as00 = &AS[0][0][0]; bf16* as01 = &AS[0][1][0];
  bf16* as10 = &AS[1][0][0]; bf16* as11 = &AS[1][1][0];
  bf16* bs00 = &BS[0][0][0]; bf16* bs01 = &BS[0][1][0];
  bf16* bs10 = &BS[1][0][0]; bf16* bs11 = &BS[1][1][0];

  // wave-local read bases (B: fold rb0 row offset)
  const bf16* Ae = &AS[0][wm][0];
  const bf16* Ao = &AS[1][wm][0];
  const bf16* Be = &BS[0][wn >> 1][rb0 * 64];
  const bf16* Bo = &BS[1][wn >> 1][rb0 * 64];

  f32x4 acc[8][4];
#pragma unroll
  for (int i = 0; i < 8; ++i)
#pragma unroll
    for (int j = 0; j < 4; ++j)
      acc[i][j] = f32x4{0.f, 0.f, 0.f, 0.f};

  bf16x8 aE0[4], aE1[4];   // A rows-half 0 (frag kk0 / kk1)
  bf16x8 aF0[4], aF1[4];   // A rows-half 1
  bf16x8 b0[4],  b1[4];    // B col-frags 0-3 (kk0 / kk1)

  // prologue: tile0 complete + tile1 {A0,A1,B0}; vmcnt(6) -> tile0 certified
  STAGE(gA0, 0, as00); STAGE(gA1, 0, as01);
  STAGE(gW0, 0, bs00); STAGE(gW1, 0, bs01);
  STAGE(gA0, 1, as10); STAGE(gA1, 1, as11);
  STAGE(gW0, 1, bs10);
  VMC(6);
  BAR();

  for (int kt = 0; kt < NT; kt += 2) {
    const int kE = (kt + 2) & (NT - 1);
    const int kO = (kt + 3) & (NT - 1);

    // PH1: read A-lo(E) 8 + B(E) j01 4; stage BO1(kt+1); MFMA Q(0,0)
    RD_A4(aE0, aE1, Ae, 0);
    RD_B2(b0, b1, Be, 0);
    STAGE(gW1, kt + 1, bs11);
    LGKM(8); BAR(); LGKM(0);
    PRIO(1); MQ(0, 0, aE0, aE1); PRIO(0); BAR();

    // PH2: read A-hi(E) 8; stage AE0(kt+2); MFMA Q(1,0)
    RD_A4(aF0, aF1, Ae, 1);
    STAGE(gA0, kE, as00);
    BAR(); LGKM(0);
    PRIO(1); MQ(4, 0, aF0, aF1); PRIO(0); BAR();

    // PH3: read B(E) j23 4; stage AE1(kt+2); MFMA Q(0,1)
    RD_B2(b0, b1, Be, 2);
    STAGE(gA1, kE, as01);
    BAR(); LGKM(0);
    PRIO(1); MQ(0, 2, aE0, aE1); PRIO(0); BAR();

    // PH4: no reads; stage BE0(kt+2); MFMA Q(1,1); vmcnt(6)
    STAGE(gW0, kE, bs00);
    BAR();
    PRIO(1); MQ(4, 2, aF0, aF1); PRIO(0);
    VMC(6); BAR();

    // PH5: read A-lo(O) + B(O) j01; stage BE1(kt+2); MFMA Q(0,0)
    RD_A4(aE0, aE1, Ao, 0);
    RD_B2(b0, b1, Bo, 0);
    STAGE(gW1, kE, bs01);
    LGKM(8); BAR(); LGKM(0);
    PRIO(1); MQ(0, 0, aE0, aE1); PRIO(0); BAR();

    // PH6: read A-hi(O); stage AO0(kt+3); MFMA Q(1,0)
    RD_A4(aF0, aF1, Ao, 1);
    STAGE(gA0, kO, as10);
    BAR(); LGKM(0);
    PRIO(1); MQ(4, 0, aF0, aF1); PRIO(0); BAR();

    // PH7: read B(O) j23; stage AO1(kt+3); MFMA Q(0,1)
    RD_B2(b0, b1, Bo, 2);
    STAGE(gA1, kO, as11);
    BAR(); LGKM(0);
    PRIO(1); MQ(0, 2, aE0, aE1); PRIO(0); BAR();

    // PH8: no reads; stage BO0(kt+3); MFMA Q(1,1); vmcnt(6)
    STAGE(gW0, kO, bs10);
    BAR();
    PRIO(1); MQ(4, 2, aF0, aF1); PRIO(0);
    VMC(6); BAR();
  }
#undef STAGE

  // epilogue: C/D layout col = lane&15, row = (lane>>4)*4 + reg
#pragma unroll
  for (int j = 0; j < 4; ++j) {
    int col = bcol + wn * 64 + j * 16 + l15;
    float bv = bias[col];
#pragma unroll
    for (int i = 0; i < 8; ++i) {
#pragma unroll
      for (int rr = 0; rr < 4; ++rr) {
        int row = brow + wm * 128 + i * 16 + lg * 4 + rr;
        float v = acc[i][j][rr] + bv;
        if (RELU) v = fmaxf(v, 0.f);
        size_t o = (size_t)row * N + col;
        if (OUTMODE == 0) outF[o] = v;
        else              outB[o] = (bf16)v;
      }
    }
  }
}

// ---------------------------------------------------------------- VQ: LDS codebook, 4-group ILP,
// packed-key argmin reduce, 1 SSE atomic/block, per-block hist flush.
__global__ __launch_bounds__(512, 2)
void vq_kernel(const float* __restrict__ latent,
               const float* __restrict__ cb, const bf16* __restrict__ cbbf_g,
               const float* __restrict__ cbnorm_g,
               bf16* __restrict__ qbf, unsigned int* __restrict__ hist,
               float* __restrict__ sse_out) {
  __shared__ bf16     cbl[NEMB * EDIM];   // 64 KB, XOR-swizzled at 16B granularity
  __shared__ float    cnl[NEMB];
  __shared__ unsigned lhist[NEMB];
  __shared__ float    swse[8];

  const int tid = threadIdx.x;
  lhist[tid] = 0;
  cnl[tid] = cbnorm_g[tid];
  {
    const uint4* src = (const uint4*)cbbf_g;   // 4096 16B units
    uint4* dst = (uint4*)cbl;
#pragma unroll
    for (int i = 0; i < 8; ++i) {
      int u = tid + i * 512;
      dst[u ^ ((u >> 3) & 7)] = src[u];
    }
  }
  __syncthreads();

  const int wave = tid >> 6, lane = tid & 63;
  const int l15 = lane & 15, lg = lane >> 4;
  const int base = blockIdx.x * 512 + wave * 64;

  bf16x8 a0[4], a1[4];
#pragma unroll
  for (int g = 0; g < 4; ++g) {
    const float* ap = latent + (size_t)(base + g * 16 + l15) * EDIM + lg * 8;
    float4 f0 = *(const float4*)(ap);
    float4 f1 = *(const float4*)(ap + 4);
    float4 f2 = *(const float4*)(ap + 32);
    float4 f3 = *(const float4*)(ap + 36);
    bf16x8 t0, t1;
    t0[0]=(bf16)f0.x; t0[1]=(bf16)f0.y; t0[2]=(bf16)f0.z; t0[3]=(bf16)f0.w;
    t0[4]=(bf16)f1.x; t0[5]=(bf16)f1.y; t0[6]=(bf16)f1.z; t0[7]=(bf16)f1.w;
    t1[0]=(bf16)f2.x; t1[1]=(bf16)f2.y; t1[2]=(bf16)f2.z; t1[3]=(bf16)f2.w;
    t1[4]=(bf16)f3.x; t1[5]=(bf16)f3.y; t1[6]=(bf16)f3.z; t1[7]=(bf16)f3.w;
    a0[g] = t0; a1[g] = t1;
  }

  float best[4][4];
  int   bidx[4][4];
#pragma unroll
  for (int g = 0; g < 4; ++g)
#pragma unroll
    for (int r = 0; r < 4; ++r) { best[g][r] = 1e30f; bidx[g][r] = 0; }

  for (int ct = 0; ct < 32; ++ct) {
    const int row = ct * 16 + l15;
    const int u0 = ((row << 3) + lg) ^ (row & 7);
    bf16x8 b0 = *(const bf16x8*)(cbl + u0 * 8);
    bf16x8 b1 = *(const bf16x8*)(cbl + (u0 ^ 4) * 8);
    float cn = cnl[row];
    int   c  = row;
#pragma unroll
    for (int g = 0; g < 4; ++g) {
      f32x4 acc = f32x4{0.f, 0.f, 0.f, 0.f};
      acc = __builtin_amdgcn_mfma_f32_16x16x32_bf16(a0[g], b0, acc, 0, 0, 0);
      acc = __builtin_amdgcn_mfma_f32_16x16x32_bf16(a1[g], b1, acc, 0, 0, 0);
#pragma unroll
      for (int r = 0; r < 4; ++r) {
        float s = fmaf(-2.0f, acc[r], cn);
        if (s < best[g][r]) { best[g][r] = s; bidx[g][r] = c; }
      }
    }
  }

  float sse = 0.f;
#pragma unroll
  for (int g = 0; g < 4; ++g) {
#pragma unroll
    for (int r = 0; r < 4; ++r) {
      uint32_t bits = __float_as_uint(best[g][r]);
      uint32_t u = bits ^ ((uint32_t)((int32_t)bits >> 31) | 0x80000000u);
      uint32_t key = (u & 0xFFFFFE00u) | (uint32_t)bidx[g][r];
#pragma unroll
      for (int m = 1; m < 16; m <<= 1) {
        uint32_t o = __shfl_xor(key, m);
        key = (o < key) ? o : key;
      }
      int idx = (int)(key & 511u);
      int rowg = base + g * 16 + lg * 4 + r;
      float4 cv = *(const float4*)(latent + (size_t)rowg * EDIM + l15 * 4);
      float4 e  = *(const float4*)(cb + (size_t)idx * EDIM + l15 * 4);
      float d0 = e.x - cv.x, d1 = e.y - cv.y, d2 = e.z - cv.z, d3 = e.w - cv.w;
      sse += d0 * d0 + d1 * d1 + d2 * d2 + d3 * d3;
      bf16x4 q;
      q[0] = (bf16)e.x; q[1] = (bf16)e.y; q[2] = (bf16)e.z; q[3] = (bf16)e.w;
      *(bf16x4*)(qbf + (size_t)rowg * EDIM + l15 * 4) = q;
      if (l15 == 0) atomicAdd(&lhist[idx], 1u);
    }
  }

#pragma unroll
  for (int m = 1; m < 64; m <<= 1) sse += __shfl_xor(sse, m);
  if (lane == 0) swse[wave] = sse;
  __syncthreads();

  unsigned v = lhist[tid];
  if (v) atomicAdd(hist + tid, v);
  if (tid == 0) {
    float s = 0.f;
#pragma unroll
    for (int w = 0; w < 8; ++w) s += swse[w];
    atomicAdd(sse_out, s);
  }
}

// ---------------------------------------------------------------- finalize: vq_loss + perplexity
__global__ void finalize_k(const unsigned* __restrict__ hist, const float* __restrict__ sse,
                           float* __restrict__ out_tail) {
  __shared__ float red[512];
  int t = threadIdx.x;
  float p = (float)hist[t] * (1.0f / (float)NCODES);
  red[t] = p * logf(p + 1e-10f);
  __syncthreads();
  for (int s = 256; s > 0; s >>= 1) {
    if (t < s) red[t] += red[t + s];
    __syncthreads();
  }
  if (t == 0) {
    out_tail[0] = 1.25f * sse[0] * (1.0f / ((float)NCODES * (float)EDIM));
    out_tail[1] = expf(-red[0]);
  }
}

// ---------------------------------------------------------------- launch
extern "C" void kernel_launch(void* const* d_in, const int* in_sizes, int n_in,
                              void* d_out, int out_size, void* d_ws, size_t ws_size,
                              hipStream_t stream) {
  const float* x  = (const float*)d_in[0];
  const float* W1 = (const float*)d_in[1];
  const float* b1 = (const float*)d_in[2];
  const float* W2 = (const float*)d_in[3];
  const float* b2 = (const float*)d_in[4];
  const float* W3 = (const float*)d_in[5];
  const float* b3 = (const float*)d_in[6];
  const float* W4 = (const float*)d_in[7];
  const float* b4 = (const float*)d_in[8];
  const float* cb = (const float*)d_in[9];
  float* out = (float*)d_out;

  char* ws = (char*)d_ws;
  float*    sse    = (float*)(ws + 0);
  unsigned* hist   = (unsigned*)(ws + 1024);
  float*    cbnorm = (float*)(ws + 4096);
  bf16*     cbbf   = (bf16*)(ws + 8192);
  size_t off = 131072;
  bf16* xbf  = (bf16*)(ws + off);  off += (size_t)NB * NF * 2;
  bf16* wbuf = (bf16*)(ws + off);  off += (size_t)NB * NF * 2;
  bf16* hbf  = (bf16*)(ws + off);  off += (size_t)NB * NF * 2;
  float* latent = (float*)(ws + off); off += (size_t)NB * NF * 4;
  bf16* qbf  = xbf;   // alias: x dead after GEMM1
  bf16* h2bf = hbf;   // alias: h dead after GEMM2

  hipMemsetAsync(ws, 0, 3072, stream);  // sse + hist

  const int n8 = NB * NF / 8;
  cvt_f32_bf16<<<dim3(2048), dim3(256), 0, stream>>>(x,  xbf,  n8);
  cvt_f32_bf16<<<dim3(2048), dim3(256), 0, stream>>>(W1, wbuf, n8);
  cbprep<<<dim3(2), dim3(256), 0, stream>>>(cb, cbbf, cbnorm);

  dim3 ggrid(256), gblock(512);
  // h = relu(x @ W1^T + b1) -> bf16
  gemm256<1, 1><<<ggrid, gblock, 0, stream>>>(xbf, wbuf, b1, (float*)nullptr, hbf);
  cvt_f32_bf16<<<dim3(2048), dim3(256), 0, stream>>>(W2, wbuf, n8);
  // latent = h @ W2^T + b2 -> f32
  gemm256<0, 0><<<ggrid, gblock, 0, stream>>>(hbf, wbuf, b2, latent, (bf16*)nullptr);
  // VQ
  vq_kernel<<<dim3(512), dim3(512), 0, stream>>>(latent, cb, cbbf, cbnorm, qbf, hist, sse);
  cvt_f32_bf16<<<dim3(2048), dim3(256), 0, stream>>>(W3, wbuf, n8);
  // h2 = relu(q @ W3^T + b3) -> bf16
  gemm256<1, 1><<<ggrid, gblock, 0, stream>>>(qbf, wbuf, b3, (float*)nullptr, h2bf);
  cvt_f32_bf16<<<dim3(2048), dim3(256), 0, stream>>>(W4, wbuf, n8);
  // recons = h2 @ W4^T + b4 -> f32 (d_out)
  gemm256<0, 0><<<ggrid, gblock, 0, stream>>>(h2bf, wbuf, b4, out, (bf16*)nullptr);

  finalize_k<<<dim3(1), dim3(512), 0, stream>>>(hist, sse, out + (size_t)NB * NF);
}

// Round 8
// 559.215 us; speedup vs baseline: 1.2663x; 1.0704x over previous
//
#include <hip/hip_runtime.h>
#include <stdint.h>
#include <stddef.h>

typedef __bf16 bf16;
typedef __bf16 bf16x8 __attribute__((ext_vector_type(8)));
typedef __bf16 bf16x4 __attribute__((ext_vector_type(4)));
typedef float  f32x4  __attribute__((ext_vector_type(4)));

#define NB      4096        // batch
#define NF      4096        // features (= K = N for all GEMMs)
#define NCODES  (NB * NF / 64)   // 262144
#define NEMB    512
#define EDIM    64

// ---------------------------------------------------------------- helpers
__device__ __forceinline__ void gld_lds16(const void* g, void* l) {
  __builtin_amdgcn_global_load_lds(
      (const __attribute__((address_space(1))) void*)g,
      (__attribute__((address_space(3))) void*)l, 16, 0, 0);
}

__device__ __forceinline__ void cvt8(const float* in, bf16* out, int i) {
  const float4* p = (const float4*)(in + (size_t)i * 8);
  float4 a = p[0], b = p[1];
  bf16x8 o;
  o[0] = (bf16)a.x; o[1] = (bf16)a.y; o[2] = (bf16)a.z; o[3] = (bf16)a.w;
  o[4] = (bf16)b.x; o[5] = (bf16)b.y; o[6] = (bf16)b.z; o[7] = (bf16)b.w;
  *(bf16x8*)(out + (size_t)i * 8) = o;
}

// ---------------------------------------------------------------- f32 -> bf16 convert
__global__ void cvt_f32_bf16(const float* __restrict__ in, bf16* __restrict__ out, int n8) {
  int idx = blockIdx.x * blockDim.x + threadIdx.x;
  int stride = gridDim.x * blockDim.x;
  for (int i = idx; i < n8; i += stride) cvt8(in, out, i);
}

// ---------------------------------------------------------------- prep: cvt(x) + cvt(W1) + cbprep
__global__ void prep_k(const float* __restrict__ x, bf16* __restrict__ xbf,
                       const float* __restrict__ w, bf16* __restrict__ wbf,
                       const float* __restrict__ cb, bf16* __restrict__ cbbf,
                       float* __restrict__ cbnorm, int n8) {
  int b = blockIdx.x, tid = threadIdx.x;
  if (b < 2048) {
    for (int i = b * 256 + tid; i < n8; i += 2048 * 256) cvt8(x, xbf, i);
  } else if (b < 4096) {
    for (int i = (b - 2048) * 256 + tid; i < n8; i += 2048 * 256) cvt8(w, wbf, i);
  } else {
    int r = (b - 4096) * 256 + tid;
    if (r < NEMB) {
      float s = 0.f;
      for (int d = 0; d < EDIM; ++d) {
        float v = cb[r * EDIM + d];
        s += v * v;
        cbbf[r * EDIM + d] = (bf16)v;
      }
      cbnorm[r] = s;
    }
  }
}

// ---------------------------------------------------------------- GEMM 256x256, 8-phase/2-tile
// (R7 schedule, frozen). MODE: 0 = f32 out (no relu), 1 = bf16 out + relu,
// 2 = fused VQ (argmin/quantize/hist/sse from the acc slab; no dense output).
#define BAR()   __builtin_amdgcn_s_barrier()
#define LGKM(n) asm volatile("s_waitcnt lgkmcnt(" #n ")" ::: "memory")
#define VMC(n)  asm volatile("s_waitcnt vmcnt(" #n ")" ::: "memory")
#define PRIO(n) __builtin_amdgcn_s_setprio(n)

#define RD_A4(d0, d1, base, rb) do {                                          \
    d0[0] = *(const bf16x8*)((base) + (rb)*4096 + 0*1024 + boff0);            \
    d1[0] = *(const bf16x8*)((base) + (rb)*4096 + 0*1024 + boff1);            \
    d0[1] = *(const bf16x8*)((base) + (rb)*4096 + 1*1024 + boff0);            \
    d1[1] = *(const bf16x8*)((base) + (rb)*4096 + 1*1024 + boff1);            \
    d0[2] = *(const bf16x8*)((base) + (rb)*4096 + 2*1024 + boff0);            \
    d1[2] = *(const bf16x8*)((base) + (rb)*4096 + 2*1024 + boff1);            \
    d0[3] = *(const bf16x8*)((base) + (rb)*4096 + 3*1024 + boff0);            \
    d1[3] = *(const bf16x8*)((base) + (rb)*4096 + 3*1024 + boff1); } while (0)

#define RD_B2(d0, d1, base, j0) do {                                          \
    d0[j0]   = *(const bf16x8*)((base) + (j0)*1024     + boff0);              \
    d1[j0]   = *(const bf16x8*)((base) + (j0)*1024     + boff1);              \
    d0[j0+1] = *(const bf16x8*)((base) + ((j0)+1)*1024 + boff0);              \
    d1[j0+1] = *(const bf16x8*)((base) + ((j0)+1)*1024 + boff1); } while (0)

#define MQ(ib, jb, A0a, A1a) do {                                             \
    _Pragma("unroll")                                                         \
    for (int fr = 0; fr < 4; ++fr) {                                          \
      _Pragma("unroll")                                                       \
      for (int jc = 0; jc < 2; ++jc) {                                        \
        acc[(ib)+fr][(jb)+jc] = __builtin_amdgcn_mfma_f32_16x16x32_bf16(      \
            A0a[fr], b0[(jb)+jc], acc[(ib)+fr][(jb)+jc], 0, 0, 0);            \
        acc[(ib)+fr][(jb)+jc] = __builtin_amdgcn_mfma_f32_16x16x32_bf16(      \
            A1a[fr], b1[(jb)+jc], acc[(ib)+fr][(jb)+jc], 0, 0, 0);            \
      } } } while (0)

template<int MODE>
__global__ __launch_bounds__(512, 2)
void gemm256(const bf16* __restrict__ A, const bf16* __restrict__ W,
             const float* __restrict__ bias,
             float* __restrict__ outF, bf16* __restrict__ outB,
             const float* __restrict__ cb, const bf16* __restrict__ cbbf,
             const float* __restrict__ cbnorm,
             unsigned int* __restrict__ hist, float* __restrict__ sse_out) {
  constexpr int K = 4096, N = 4096, NT = 64;
  __shared__ bf16 SM[65536];          // 128 KB: AS = SM[0..32768), BS = SM[32768..)
  __shared__ unsigned lhist[NEMB];    // VQ epilogue only
  __shared__ float swse[8];

  const int tid = threadIdx.x;
  const int wave = tid >> 6, lane = tid & 63;
  const int l15 = lane & 15, lg = lane >> 4;
  const int wm = wave >> 2, wn = wave & 3;
  const int rb0 = (wn & 1) * 64;

  // XCD-bijective swizzle (256 blocks, 256 % 8 == 0)
  const int bid = blockIdx.x;
  const int lb  = (bid & 7) * 32 + (bid >> 3);
  const int bx = lb & 15, by = lb >> 4;
  const int brow = by * 256, bcol = bx * 256;

  // hoisted per-lane ds_read bases
  const int boff0 = l15 * 64 + ((lg ^ (l15 & 7)) * 8);
  const int boff1 = boff0 ^ 32;

  // staging: thread covers units u1,u2 of each 1024-unit half-tile
  const int u1 = tid,       r1 = u1 >> 3, ss1 = (u1 & 7) ^ (r1 & 7);
  const int u2 = tid + 512, r2 = u2 >> 3, ss2 = (u2 & 7) ^ (r2 & 7);
  const size_t tofs1 = (size_t)r1 * K + ss1 * 8;
  const size_t tofs2 = (size_t)r2 * K + ss2 * 8;
  const bf16* gW0 = W + (size_t)bcol * K;
  const bf16* gW1 = W + (size_t)(bcol + 128) * K;
  const bf16* gA0 = A + (size_t)brow * K;
  const bf16* gA1 = A + (size_t)(brow + 128) * K;

#define STAGE(gptr, k_, ldsh) do {                                        \
    gld_lds16((gptr) + tofs1 + (size_t)(k_) * 64, (ldsh) + u1 * 8);       \
    gld_lds16((gptr) + tofs2 + (size_t)(k_) * 64, (ldsh) + u2 * 8); } while (0)

  bf16* as00 = SM;         bf16* as01 = SM + 8192;
  bf16* as10 = SM + 16384; bf16* as11 = SM + 24576;
  bf16* bs00 = SM + 32768; bf16* bs01 = SM + 40960;
  bf16* bs10 = SM + 49152; bf16* bs11 = SM + 57344;

  const bf16* Ae = SM + wm * 8192;
  const bf16* Ao = SM + 16384 + wm * 8192;
  const bf16* Be = SM + 32768 + (wn >> 1) * 8192 + rb0 * 64;
  const bf16* Bo = SM + 49152 + (wn >> 1) * 8192 + rb0 * 64;

  f32x4 acc[8][4];
#pragma unroll
  for (int i = 0; i < 8; ++i)
#pragma unroll
    for (int j = 0; j < 4; ++j)
      acc[i][j] = f32x4{0.f, 0.f, 0.f, 0.f};

  bf16x8 aE0[4], aE1[4];
  bf16x8 aF0[4], aF1[4];
  bf16x8 b0[4],  b1[4];

  // prologue: tile0 complete + tile1 {A0,A1,B0}; vmcnt(6) -> tile0 certified
  STAGE(gA0, 0, as00); STAGE(gA1, 0, as01);
  STAGE(gW0, 0, bs00); STAGE(gW1, 0, bs01);
  STAGE(gA0, 1, as10); STAGE(gA1, 1, as11);
  STAGE(gW0, 1, bs10);
  VMC(6);
  BAR();

  for (int kt = 0; kt < NT; kt += 2) {
    const int kE = (kt + 2) & (NT - 1);
    const int kO = (kt + 3) & (NT - 1);

    // PH1
    RD_A4(aE0, aE1, Ae, 0);
    RD_B2(b0, b1, Be, 0);
    STAGE(gW1, kt + 1, bs11);
    LGKM(8); BAR(); LGKM(0);
    PRIO(1); MQ(0, 0, aE0, aE1); PRIO(0); BAR();

    // PH2
    RD_A4(aF0, aF1, Ae, 1);
    STAGE(gA0, kE, as00);
    BAR(); LGKM(0);
    PRIO(1); MQ(4, 0, aF0, aF1); PRIO(0); BAR();

    // PH3
    RD_B2(b0, b1, Be, 2);
    STAGE(gA1, kE, as01);
    BAR(); LGKM(0);
    PRIO(1); MQ(0, 2, aE0, aE1); PRIO(0); BAR();

    // PH4
    STAGE(gW0, kE, bs00);
    BAR();
    PRIO(1); MQ(4, 2, aF0, aF1); PRIO(0);
    VMC(6); BAR();

    // PH5
    RD_A4(aE0, aE1, Ao, 0);
    RD_B2(b0, b1, Bo, 0);
    STAGE(gW1, kE, bs01);
    LGKM(8); BAR(); LGKM(0);
    PRIO(1); MQ(0, 0, aE0, aE1); PRIO(0); BAR();

    // PH6
    RD_A4(aF0, aF1, Ao, 1);
    STAGE(gA0, kO, as10);
    BAR(); LGKM(0);
    PRIO(1); MQ(4, 0, aF0, aF1); PRIO(0); BAR();

    // PH7
    RD_B2(b0, b1, Bo, 2);
    STAGE(gA1, kO, as11);
    BAR(); LGKM(0);
    PRIO(1); MQ(0, 2, aE0, aE1); PRIO(0); BAR();

    // PH8
    STAGE(gW0, kO, bs10);
    BAR();
    PRIO(1); MQ(4, 2, aF0, aF1); PRIO(0);
    VMC(6); BAR();
  }
#undef STAGE

  if (MODE == 2) {
    // -------- fused VQ epilogue --------
    __syncthreads();                 // all LDS reads of the K-loop done
    lhist[tid] = 0;
    // write (acc + bias) as bf16 codes into wave-private swizzled scratch
    bf16* scr = SM + wave * 8192;    // 128 rows x 64 dims, same swizzle geometry
#pragma unroll
    for (int j = 0; j < 4; ++j) {
      float bv = bias[bcol + wn * 64 + j * 16 + l15];
#pragma unroll
      for (int i = 0; i < 8; ++i) {
#pragma unroll
        for (int rr = 0; rr < 4; ++rr) {
          int r = i * 16 + lg * 4 + rr;
          int d = j * 16 + l15;
          scr[r * 64 + (((d >> 3) ^ (r & 7)) << 3) + (d & 7)] =
              (bf16)(acc[i][j][rr] + bv);
        }
      }
    }
    __syncthreads();                 // lhist zeroed (scratch is wave-private)

    // load all 8 code-groups as A-frags (same pattern as main-loop Ae reads)
    bf16x8 ca0[8], ca1[8];
#pragma unroll
    for (int g = 0; g < 8; ++g) {
      ca0[g] = *(const bf16x8*)(scr + g * 1024 + boff0);
      ca1[g] = *(const bf16x8*)(scr + g * 1024 + boff1);
    }
    float best[8][4];
    int   bidx[8][4];
#pragma unroll
    for (int g = 0; g < 8; ++g)
#pragma unroll
      for (int r = 0; r < 4; ++r) { best[g][r] = 1e30f; bidx[g][r] = 0; }

#pragma unroll 4
    for (int ct = 0; ct < 32; ++ct) {
      const bf16* bp = cbbf + (ct * 16 + l15) * 64 + lg * 8;
      bf16x8 q0 = *(const bf16x8*)bp;
      bf16x8 q1 = *(const bf16x8*)(bp + 32);
      float cn = cbnorm[ct * 16 + l15];
      int c = ct * 16 + l15;
#pragma unroll
      for (int g = 0; g < 8; ++g) {
        f32x4 da = f32x4{0.f, 0.f, 0.f, 0.f};
        da = __builtin_amdgcn_mfma_f32_16x16x32_bf16(ca0[g], q0, da, 0, 0, 0);
        da = __builtin_amdgcn_mfma_f32_16x16x32_bf16(ca1[g], q1, da, 0, 0, 0);
#pragma unroll
        for (int r = 0; r < 4; ++r) {
          float s = fmaf(-2.0f, da[r], cn);
          if (s < best[g][r]) { best[g][r] = s; bidx[g][r] = c; }
        }
      }
    }

    float sse = 0.f;
    const int gcol = bcol + wn * 64;
#pragma unroll
    for (int g = 0; g < 8; ++g) {
#pragma unroll
      for (int r = 0; r < 4; ++r) {
        uint32_t bits = __float_as_uint(best[g][r]);
        uint32_t u = bits ^ ((uint32_t)((int32_t)bits >> 31) | 0x80000000u);
        uint32_t key = (u & 0xFFFFFE00u) | (uint32_t)bidx[g][r];
#pragma unroll
        for (int m = 1; m < 16; m <<= 1) {
          uint32_t o = __shfl_xor(key, m);
          key = (o < key) ? o : key;
        }
        int idx = (int)(key & 511u);
        int rowl = g * 16 + lg * 4 + r;
        bf16x4 cv = *(const bf16x4*)(scr + rowl * 64 +
                        (((l15 >> 1) ^ (rowl & 7)) << 3) + (l15 & 1) * 4);
        float4 e = *(const float4*)(cb + (size_t)idx * EDIM + l15 * 4);
        float d0 = e.x - (float)cv[0], d1 = e.y - (float)cv[1];
        float d2 = e.z - (float)cv[2], d3 = e.w - (float)cv[3];
        sse += d0 * d0 + d1 * d1 + d2 * d2 + d3 * d3;
        bf16x4 qv;
        qv[0] = (bf16)e.x; qv[1] = (bf16)e.y; qv[2] = (bf16)e.z; qv[3] = (bf16)e.w;
        *(bf16x4*)(outB + (size_t)(brow + wm * 128 + rowl) * N + gcol + l15 * 4) = qv;
        if (l15 == 0) atomicAdd(&lhist[idx], 1u);
      }
    }
#pragma unroll
    for (int m = 1; m < 64; m <<= 1) sse += __shfl_xor(sse, m);
    if (lane == 0) swse[wave] = sse;
    __syncthreads();
    { unsigned v = lhist[tid]; if (v) atomicAdd(hist + tid, v); }
    if (tid == 0) {
      float s = 0.f;
#pragma unroll
      for (int w = 0; w < 8; ++w) s += swse[w];
      atomicAdd(sse_out, s);
    }
    return;
  }

  // -------- dense epilogue (MODE 0/1) --------
#pragma unroll
  for (int j = 0; j < 4; ++j) {
    int col = bcol + wn * 64 + j * 16 + l15;
    float bv = bias[col];
#pragma unroll
    for (int i = 0; i < 8; ++i) {
#pragma unroll
      for (int rr = 0; rr < 4; ++rr) {
        int row = brow + wm * 128 + i * 16 + lg * 4 + rr;
        float v = acc[i][j][rr] + bv;
        if (MODE == 1) v = fmaxf(v, 0.f);
        size_t o = (size_t)row * N + col;
        if (MODE == 0) outF[o] = v;
        else           outB[o] = (bf16)v;
      }
    }
  }
}

// ---------------------------------------------------------------- finalize: vq_loss + perplexity
__global__ void finalize_k(const unsigned* __restrict__ hist, const float* __restrict__ sse,
                           float* __restrict__ out_tail) {
  __shared__ float red[512];
  int t = threadIdx.x;
  float p = (float)hist[t] * (1.0f / (float)NCODES);
  red[t] = p * logf(p + 1e-10f);
  __syncthreads();
  for (int s = 256; s > 0; s >>= 1) {
    if (t < s) red[t] += red[t + s];
    __syncthreads();
  }
  if (t == 0) {
    out_tail[0] = 1.25f * sse[0] * (1.0f / ((float)NCODES * (float)EDIM));
    out_tail[1] = expf(-red[0]);
  }
}

// ---------------------------------------------------------------- launch
extern "C" void kernel_launch(void* const* d_in, const int* in_sizes, int n_in,
                              void* d_out, int out_size, void* d_ws, size_t ws_size,
                              hipStream_t stream) {
  const float* x  = (const float*)d_in[0];
  const float* W1 = (const float*)d_in[1];
  const float* b1 = (const float*)d_in[2];
  const float* W2 = (const float*)d_in[3];
  const float* b2 = (const float*)d_in[4];
  const float* W3 = (const float*)d_in[5];
  const float* b3 = (const float*)d_in[6];
  const float* W4 = (const float*)d_in[7];
  const float* b4 = (const float*)d_in[8];
  const float* cb = (const float*)d_in[9];
  float* out = (float*)d_out;

  char* ws = (char*)d_ws;
  float*    sse    = (float*)(ws + 0);
  unsigned* hist   = (unsigned*)(ws + 1024);
  float*    cbnorm = (float*)(ws + 4096);
  bf16*     cbbf   = (bf16*)(ws + 8192);
  size_t off = 131072;
  bf16* xbf  = (bf16*)(ws + off);  off += (size_t)NB * NF * 2;
  bf16* wbuf = (bf16*)(ws + off);  off += (size_t)NB * NF * 2;
  bf16* hbf  = (bf16*)(ws + off);  off += (size_t)NB * NF * 2;
  bf16* qbf  = xbf;   // alias: x dead after GEMM1
  bf16* h2bf = hbf;   // alias: h dead after GEMM2(VQ)

  hipMemsetAsync(ws, 0, 3072, stream);  // sse + hist

  const int n8 = NB * NF / 8;
  prep_k<<<dim3(4098), dim3(256), 0, stream>>>(x, xbf, W1, wbuf, cb, cbbf, cbnorm, n8);

  dim3 ggrid(256), gblock(512);
  // h = relu(x @ W1^T + b1) -> bf16
  gemm256<1><<<ggrid, gblock, 0, stream>>>(xbf, wbuf, b1, nullptr, hbf,
                                           nullptr, nullptr, nullptr, nullptr, nullptr);
  cvt_f32_bf16<<<dim3(2048), dim3(256), 0, stream>>>(W2, wbuf, n8);
  // latent = h @ W2^T + b2, fused VQ -> qbf + hist + sse
  gemm256<2><<<ggrid, gblock, 0, stream>>>(hbf, wbuf, b2, nullptr, qbf,
                                           cb, cbbf, cbnorm, hist, sse);
  cvt_f32_bf16<<<dim3(2048), dim3(256), 0, stream>>>(W3, wbuf, n8);
  // h2 = relu(q @ W3^T + b3) -> bf16
  gemm256<1><<<ggrid, gblock, 0, stream>>>(qbf, wbuf, b3, nullptr, h2bf,
                                           nullptr, nullptr, nullptr, nullptr, nullptr);
  cvt_f32_bf16<<<dim3(2048), dim3(256), 0, stream>>>(W4, wbuf, n8);
  // recons = h2 @ W4^T + b4 -> f32 (d_out)
  gemm256<0><<<ggrid, gblock, 0, stream>>>(h2bf, wbuf, b4, out, nullptr,
                                           nullptr, nullptr, nullptr, nullptr, nullptr);

  finalize_k<<<dim3(1), dim3(512), 0, stream>>>(hist, sse, out + (size_t)NB * NF);
}